// Round 10
// baseline (266.234 us; speedup 1.0000x reference)
//
#include <hip/hip_runtime.h>

#define LUT_N 4096
#define DVAL  4096
#define TPB   512    // 2 rows per block: 32 KB LUT shared by 8 waves

static constexpr double TWO_PI_D = 6.283185307179586476925286766559;
#define PHI_F 1.61803398874989484820f

// ---------- helpers ----------
__device__ __forceinline__ float fc(const float4& f, int j) {
    switch (j) { case 0: return f.x; case 1: return f.y; case 2: return f.z; }
    return f.w;
}
__device__ __forceinline__ void sc4(float4& f, int j, float v) {
    switch (j) { case 0: f.x = v; return; case 1: f.y = v; return; case 2: f.z = v; return; }
    f.w = v;
}
// jnp: idx = mod(round(theta*(N/2pi)).astype(int32), N). rintf = round-half-even,
// single final & 4095 == Python mod for pow2 ((a&m + b&m)&m == (a+b)&m).
__device__ __forceinline__ int lut_round(float theta, float cidx) {
    return (int)rintf(theta * cidx);
}

// ---------- precompute: LUT + per-column reciprocals ----------
__global__ __launch_bounds__(256) void echo_precompute(
    const float* __restrict__ w_query,
    const float* __restrict__ w_out,
    const float* __restrict__ beta,
    float2* __restrict__ lut,   // [LUT_N] {sin, cos}
    float*  __restrict__ invq,  // [D] 1/(1+|w_query|)
    float*  __restrict__ wsi)   // [D] write_scale/wavelength
{
    int i = blockIdx.x * 256 + threadIdx.x;
    const float c2 = (float)(TWO_PI_D / (double)LUT_N);
    if (i < LUT_N) {
        float ang = (float)i * c2;               // matches arange(N)*(2pi/N) in f32
        lut[i] = make_float2(sinf(ang), cosf(ang));
    }
    if (i < DVAL) {
        float inv_q     = 1.0f / (1.0f + fabsf(w_query[i]));   // IEEE divide, once per column
        float w_eff     = 1.0f / (1.0f + fabsf(w_out[i]));
        float beta_eff  = 1.0f / (1.0f + fabsf(beta[i]));
        float decay     = fminf(expf(-beta_eff * w_eff), 0.9999f);
        invq[i] = inv_q;
        wsi[i]  = (w_eff * (1.0f - decay)) * w_eff;            // write_scale * (1/wavelength)
    }
}

// ---------- main fused kernel: one block = TWO batch rows (waves 0-3 / 4-7) ----------
// launch_bounds(512,4): 128-VGPR budget -> compiler can batch-issue the unrolled
// loads + 16 independent LDS gathers per stage (VGPR=32 in r8 serialized them).
template<bool USE_WS>
__global__ __launch_bounds__(TPB, 4) void echo_main(
    const float* __restrict__ x_real,
    const float* __restrict__ x_imag,
    const float* __restrict__ t,
    const float* __restrict__ trig_r,
    const float* __restrict__ trig_i,
    const float* __restrict__ w_query,
    const float* __restrict__ b_query,
    const float* __restrict__ w_out,
    const float* __restrict__ b_out,
    const float* __restrict__ beta,
    const float2* __restrict__ lutG,
    const float*  __restrict__ invqG,
    const float*  __restrict__ wsiG,
    float* __restrict__ out,
    int B)
{
    __shared__ float2 lutS[LUT_N];   // 32 KB, shared by both rows
    __shared__ float redR[8], redI[8];
    __shared__ float magS[2];

    const int tid  = threadIdx.x;
    const int half = tid >> 8;             // 0: first row, 1: second row
    const int lane = tid & 255;            // thread index within the row
    int row = blockIdx.x * 2 + half;
    if (row >= B) row = B - 1;             // odd-B safety
    const float cidx = (float)((double)LUT_N / TWO_PI_D);  // 651.89865f

    // stage the LUT into LDS (512 threads x 4 float4 = 2048 float4 = 4096 float2)
    if constexpr (USE_WS) {
        const float4* src = (const float4*)lutG;
        float4* dst = (float4*)lutS;
        #pragma unroll
        for (int k = 0; k < 4; ++k) {
            int idx = tid + TPB * k;
            dst[idx] = src[idx];
        }
    } else {
        const float c2 = (float)(TWO_PI_D / (double)LUT_N);
        #pragma unroll
        for (int k = 0; k < 8; ++k) {
            int idx = tid + TPB * k;
            float ang = (float)idx * c2;
            lutS[idx] = make_float2(sinf(ang), cosf(ang));
        }
    }

    const float tphi = t[row] * PHI_F;
    const float* xr = x_real + (size_t)row * DVAL;
    const float* xi = x_imag + (size_t)row * DVAL;

    float4 xr_s[4], xi_s[4];
    float accr = 0.0f, acci = 0.0f;

    __syncthreads();

    // ---- stage 1: per-head interference, reduced over the whole row ----
    // q = exp(i*(theta_r+theta_i)) on the quantized grid -> single float2 gather.
    #pragma unroll
    for (int k = 0; k < 4; ++k) {
        int v = lane + 256 * k;            // float4 index within row (1024 per row)
        float4 a = ((const float4*)xr)[v];
        float4 c = ((const float4*)xi)[v];
        xr_s[k] = a; xi_s[k] = c;

        float4 iv4;
        if constexpr (USE_WS) {
            iv4 = ((const float4*)invqG)[v];
        } else {
            float4 wq4 = ((const float4*)w_query)[v];
            iv4 = make_float4(1.0f / (1.0f + fabsf(wq4.x)), 1.0f / (1.0f + fabsf(wq4.y)),
                              1.0f / (1.0f + fabsf(wq4.z)), 1.0f / (1.0f + fabsf(wq4.w)));
        }
        float4 bq4 = ((const float4*)b_query)[v];
        float4 tr4 = ((const float4*)trig_r)[v];
        float4 ti4 = ((const float4*)trig_i)[v];

        #pragma unroll
        for (int j = 0; j < 4; ++j) {
            float iv = fc(iv4, j), bq = fc(bq4, j);
            float thr = __builtin_fmaf(fc(a, j), iv, bq) + tphi;   // ref add order kept
            float thi = __builtin_fmaf(fc(c, j), iv, bq) + tphi;
            int idx = (lut_round(thr, cidx) + lut_round(thi, cidx)) & (LUT_N - 1);
            float2 s = lutS[idx];          // {sin, cos} of angle sum
            float q_r = s.y, q_i = s.x;
            accr = __builtin_fmaf(q_r, fc(tr4, j), __builtin_fmaf(q_i, fc(ti4, j), accr));
            acci = __builtin_fmaf(q_r, fc(ti4, j), __builtin_fmaf(-q_i, fc(tr4, j), acci));
        }
    }

    // ---- prefetch stage-2 per-column operands BEFORE the reduction barriers ----
    // Their latency hides under the shuffle-reduce + two __syncthreads.
    float4 ws_s[4], bo_s[4];
    #pragma unroll
    for (int k = 0; k < 4; ++k) {
        int v = lane + 256 * k;
        if constexpr (USE_WS) {
            ws_s[k] = ((const float4*)wsiG)[v];
        } else {
            float4 wo4 = ((const float4*)w_out)[v];
            float4 be4 = ((const float4*)beta)[v];
            #pragma unroll
            for (int j = 0; j < 4; ++j) {
                float w_eff = 1.0f / (1.0f + fabsf(fc(wo4, j)));
                float beta_eff = 1.0f / (1.0f + fabsf(fc(be4, j)));
                float decay = fminf(expf(-beta_eff * w_eff), 0.9999f);
                sc4(ws_s[k], j, (w_eff * (1.0f - decay)) * w_eff);
            }
        }
        bo_s[k] = ((const float4*)b_out)[v];
    }

    // ---- per-row block reduction -> int_mag ----
    #pragma unroll
    for (int m = 32; m >= 1; m >>= 1) {
        accr += __shfl_xor(accr, m, 64);
        acci += __shfl_xor(acci, m, 64);
    }
    const int wave = tid >> 6;             // 0..7; waves 0-3 = row A, 4-7 = row B
    if ((tid & 63) == 0) { redR[wave] = accr; redI[wave] = acci; }
    __syncthreads();
    if (lane == 0) {                       // tid==0 and tid==256
        int o = half * 4;
        float tr = (redR[o] + redR[o+1] + redR[o+2] + redR[o+3]) * 0.0625f; // mean over 16 heads
        float ti = (redI[o] + redI[o+1] + redI[o+2] + redI[o+3]) * 0.0625f;
        magS[half] = sqrtf(tr * tr + ti * ti + 1e-8f);
    }
    __syncthreads();
    const float mag = magS[half];

    // ---- stage 2: memory write + Euler projection (operands already in regs) ----
    float4* outR = (float4*)(out + (size_t)row * DVAL);
    float4* outI = (float4*)(out + (size_t)B * DVAL + (size_t)row * DVAL);

    #pragma unroll
    for (int k = 0; k < 4; ++k) {
        int v = lane + 256 * k;
        float4 oR, oI;
        #pragma unroll
        for (int j = 0; j < 4; ++j) {
            float wsi_j = fc(ws_s[k], j), bo = fc(bo_s[k], j);
            float xmr = fc(xr_s[k], j) * mag;
            float xmi = fc(xi_s[k], j) * mag;
            float thr = __builtin_fmaf(xmr, wsi_j, bo) + tphi;
            float thi = __builtin_fmaf(xmi, wsi_j, bo) + tphi;
            int idx = (lut_round(thr, cidx) + lut_round(thi, cidx)) & (LUT_N - 1);
            float2 s = lutS[idx];
            sc4(oR, j, s.y);   // cos(sum)
            sc4(oI, j, s.x);   // sin(sum)
        }
        outR[v] = oR;          // plain stores: complete in L2/L3, drain async
        outI[v] = oI;
    }
}

extern "C" void kernel_launch(void* const* d_in, const int* in_sizes, int n_in,
                              void* d_out, int out_size, void* d_ws, size_t ws_size,
                              hipStream_t stream) {
    const float* x_real    = (const float*)d_in[0];
    const float* x_imag    = (const float*)d_in[1];
    const float* t         = (const float*)d_in[2];
    const float* trig_r    = (const float*)d_in[3];
    const float* trig_i    = (const float*)d_in[4];
    const float* w_query   = (const float*)d_in[5];
    const float* b_query   = (const float*)d_in[6];
    const float* w_out     = (const float*)d_in[7];
    const float* b_out     = (const float*)d_in[8];
    const float* beta      = (const float*)d_in[9];
    float* out = (float*)d_out;

    const int B = in_sizes[2];          // 4096
    const int nblocks = (B + 1) / 2;    // 2 rows per block
    const size_t need = (size_t)LUT_N * sizeof(float2) + 2 * (size_t)DVAL * sizeof(float);

    if (d_ws != nullptr && ws_size >= need) {
        char* ws = (char*)d_ws;
        float2* lut  = (float2*)ws;
        float*  invq = (float*)(ws + (size_t)LUT_N * sizeof(float2));
        float*  wsi  = invq + DVAL;
        echo_precompute<<<(LUT_N > DVAL ? LUT_N : DVAL) / 256, 256, 0, stream>>>(
            w_query, w_out, beta, lut, invq, wsi);
        echo_main<true><<<nblocks, TPB, 0, stream>>>(
            x_real, x_imag, t, trig_r, trig_i, w_query, b_query, w_out, b_out, beta,
            lut, invq, wsi, out, B);
    } else {
        echo_main<false><<<nblocks, TPB, 0, stream>>>(
            x_real, x_imag, t, trig_r, trig_i, w_query, b_query, w_out, b_out, beta,
            nullptr, nullptr, nullptr, out, B);
    }
}

// Round 13
// 261.809 us; speedup vs baseline: 1.0169x; 1.0169x over previous
//
#include <hip/hip_runtime.h>

#define LUT_N 4096
#define DVAL  4096
#define TPB   256

static constexpr double TWO_PI_D = 6.283185307179586476925286766559;
#define PHI_F 1.61803398874989484820f

// ---------- helpers ----------
__device__ __forceinline__ float fc(const float4& f, int j) {
    switch (j) { case 0: return f.x; case 1: return f.y; case 2: return f.z; }
    return f.w;
}
__device__ __forceinline__ void sc4(float4& f, int j, float v) {
    switch (j) { case 0: f.x = v; return; case 1: f.y = v; return; case 2: f.z = v; return; }
    f.w = v;
}
// Reference: idx = mod(round(theta*(N/2pi)), N); value = table[idx] = sinf/cosf(idx*step).
// We keep the identical quantization (rintf = round-half-even = jnp.round) but evaluate
// sin/cos(idx*step) directly with the HW trans ops, whose input is in REVOLUTIONS:
//   v_sin(frac) = sin(2*pi*frac),  frac = fract((r+s)/4096) == ((ir+ii) mod 4096)/4096
// exactly (|r+s| < 2^24 so all float steps are exact). Angle diff vs the f32 table
// argument is idx*(2pi/4096 - f32(2pi/4096)) <= 5e-7 -> ~1e-6 output error, far below
// the validated 0.0039 absmax.
__device__ __forceinline__ void grid_sincos(float thr, float thi, float cidx,
                                            float& s_out, float& c_out) {
    float r = rintf(thr * cidx);
    float s = rintf(thi * cidx);
    float rev = (r + s) * (1.0f / (float)LUT_N);
    float frac = rev - floorf(rev);          // == fract, handles negatives
    s_out = __builtin_amdgcn_sinf(frac);     // v_sin_f32: sin(2*pi*frac)
    c_out = __builtin_amdgcn_cosf(frac);     // v_cos_f32: cos(2*pi*frac)
}

// ---------- precompute: per-column reciprocals (no LUT anymore) ----------
__global__ __launch_bounds__(256) void echo_precompute(
    const float* __restrict__ w_query,
    const float* __restrict__ w_out,
    const float* __restrict__ beta,
    float* __restrict__ invq,  // [D] 1/(1+|w_query|)
    float* __restrict__ wsi)   // [D] write_scale/wavelength
{
    int i = blockIdx.x * 256 + threadIdx.x;
    if (i < DVAL) {
        float inv_q     = 1.0f / (1.0f + fabsf(w_query[i]));   // IEEE divide, once per column
        float w_eff     = 1.0f / (1.0f + fabsf(w_out[i]));
        float beta_eff  = 1.0f / (1.0f + fabsf(beta[i]));
        float decay     = fminf(expf(-beta_eff * w_eff), 0.9999f);
        invq[i] = inv_q;
        wsi[i]  = (w_eff * (1.0f - decay)) * w_eff;            // write_scale * (1/wavelength)
    }
}

// ---------- main fused kernel: one block per batch row, no LDS LUT ----------
template<bool USE_WS>
__global__ __launch_bounds__(TPB, 4) void echo_main(
    const float* __restrict__ x_real,
    const float* __restrict__ x_imag,
    const float* __restrict__ t,
    const float* __restrict__ trig_r,
    const float* __restrict__ trig_i,
    const float* __restrict__ w_query,
    const float* __restrict__ b_query,
    const float* __restrict__ w_out,
    const float* __restrict__ b_out,
    const float* __restrict__ beta,
    const float* __restrict__ invqG,
    const float* __restrict__ wsiG,
    float* __restrict__ out,
    int B)
{
    __shared__ float redR[4], redI[4];
    __shared__ float magS;

    const int tid = threadIdx.x;
    const int row = blockIdx.x;
    const float cidx = (float)((double)LUT_N / TWO_PI_D);  // 651.89865f

    const float tphi = t[row] * PHI_F;
    const float* xr = x_real + (size_t)row * DVAL;
    const float* xi = x_imag + (size_t)row * DVAL;

    float4 xr_s[4], xi_s[4];
    float accr = 0.0f, acci = 0.0f;

    // ---- stage 1: per-head interference, reduced over the whole row ----
    #pragma unroll
    for (int k = 0; k < 4; ++k) {
        int v = tid + TPB * k;             // float4 index within row (1024 per row)
        float4 a = ((const float4*)xr)[v];
        float4 c = ((const float4*)xi)[v];
        xr_s[k] = a; xi_s[k] = c;

        float4 iv4;
        if constexpr (USE_WS) {
            iv4 = ((const float4*)invqG)[v];
        } else {
            float4 wq4 = ((const float4*)w_query)[v];
            iv4 = make_float4(1.0f / (1.0f + fabsf(wq4.x)), 1.0f / (1.0f + fabsf(wq4.y)),
                              1.0f / (1.0f + fabsf(wq4.z)), 1.0f / (1.0f + fabsf(wq4.w)));
        }
        float4 bq4 = ((const float4*)b_query)[v];
        float4 tr4 = ((const float4*)trig_r)[v];
        float4 ti4 = ((const float4*)trig_i)[v];

        #pragma unroll
        for (int j = 0; j < 4; ++j) {
            float iv = fc(iv4, j), bq = fc(bq4, j);
            float thr = __builtin_fmaf(fc(a, j), iv, bq) + tphi;   // ref add order kept
            float thi = __builtin_fmaf(fc(c, j), iv, bq) + tphi;
            float q_i, q_r;
            grid_sincos(thr, thi, cidx, q_i, q_r);   // sin(sum), cos(sum)
            accr = __builtin_fmaf(q_r, fc(tr4, j), __builtin_fmaf(q_i, fc(ti4, j), accr));
            acci = __builtin_fmaf(q_r, fc(ti4, j), __builtin_fmaf(-q_i, fc(tr4, j), acci));
        }
    }

    // ---- per-row block reduction -> int_mag (same tree as validated r3 kernel) ----
    #pragma unroll
    for (int m = 32; m >= 1; m >>= 1) {
        accr += __shfl_xor(accr, m, 64);
        acci += __shfl_xor(acci, m, 64);
    }
    if ((tid & 63) == 0) { redR[tid >> 6] = accr; redI[tid >> 6] = acci; }
    __syncthreads();
    if (tid == 0) {
        float tr = (redR[0] + redR[1] + redR[2] + redR[3]) * 0.0625f; // mean over 16 heads
        float ti = (redI[0] + redI[1] + redI[2] + redI[3]) * 0.0625f;
        magS = sqrtf(tr * tr + ti * ti + 1e-8f);
    }
    __syncthreads();
    const float mag = magS;

    // ---- stage 2: memory write + Euler projection ----
    float4* outR = (float4*)(out + (size_t)row * DVAL);
    float4* outI = (float4*)(out + (size_t)B * DVAL + (size_t)row * DVAL);

    #pragma unroll
    for (int k = 0; k < 4; ++k) {
        int v = tid + TPB * k;
        float4 ws4;
        if constexpr (USE_WS) {
            ws4 = ((const float4*)wsiG)[v];
        } else {
            float4 wo4 = ((const float4*)w_out)[v];
            float4 be4 = ((const float4*)beta)[v];
            #pragma unroll
            for (int j = 0; j < 4; ++j) {
                float w_eff = 1.0f / (1.0f + fabsf(fc(wo4, j)));
                float beta_eff = 1.0f / (1.0f + fabsf(fc(be4, j)));
                float decay = fminf(expf(-beta_eff * w_eff), 0.9999f);
                sc4(ws4, j, (w_eff * (1.0f - decay)) * w_eff);
            }
        }
        float4 bo4 = ((const float4*)b_out)[v];

        float4 oR, oI;
        #pragma unroll
        for (int j = 0; j < 4; ++j) {
            float wsi_j = fc(ws4, j), bo = fc(bo4, j);
            float xmr = fc(xr_s[k], j) * mag;
            float xmi = fc(xi_s[k], j) * mag;
            float thr = __builtin_fmaf(xmr, wsi_j, bo) + tphi;
            float thi = __builtin_fmaf(xmi, wsi_j, bo) + tphi;
            float s_o, c_o;
            grid_sincos(thr, thi, cidx, s_o, c_o);
            sc4(oR, j, c_o);   // cos(sum)
            sc4(oI, j, s_o);   // sin(sum)
        }
        outR[v] = oR;
        outI[v] = oI;
    }
}

extern "C" void kernel_launch(void* const* d_in, const int* in_sizes, int n_in,
                              void* d_out, int out_size, void* d_ws, size_t ws_size,
                              hipStream_t stream) {
    const float* x_real    = (const float*)d_in[0];
    const float* x_imag    = (const float*)d_in[1];
    const float* t         = (const float*)d_in[2];
    const float* trig_r    = (const float*)d_in[3];
    const float* trig_i    = (const float*)d_in[4];
    const float* w_query   = (const float*)d_in[5];
    const float* b_query   = (const float*)d_in[6];
    const float* w_out     = (const float*)d_in[7];
    const float* b_out     = (const float*)d_in[8];
    const float* beta      = (const float*)d_in[9];
    float* out = (float*)d_out;

    const int B = in_sizes[2];          // 4096
    const size_t need = 2 * (size_t)DVAL * sizeof(float);

    if (d_ws != nullptr && ws_size >= need) {
        float* invq = (float*)d_ws;
        float* wsi  = invq + DVAL;
        echo_precompute<<<DVAL / 256, 256, 0, stream>>>(w_query, w_out, beta, invq, wsi);
        echo_main<true><<<B, TPB, 0, stream>>>(
            x_real, x_imag, t, trig_r, trig_i, w_query, b_query, w_out, b_out, beta,
            invq, wsi, out, B);
    } else {
        echo_main<false><<<B, TPB, 0, stream>>>(
            x_real, x_imag, t, trig_r, trig_i, w_query, b_query, w_out, b_out, beta,
            nullptr, nullptr, out, B);
    }
}